// Round 12
// baseline (405.368 us; speedup 1.0000x reference)
//
#include <hip/hip_runtime.h>

typedef _Float16 f16;
typedef _Float16 half8 __attribute__((ext_vector_type(8)));
typedef _Float16 half4 __attribute__((ext_vector_type(4)));
typedef float floatx4 __attribute__((ext_vector_type(4)));

#define MFMA16(a, b, c) __builtin_amdgcn_mfma_f32_16x16x32_f16(a, b, c, 0, 0, 0)

// counted-vmcnt phase gate: wait until only the NEXT tile's 4 staging loads
// remain in flight (FIFO: current tile's 4 are older -> retired first),
// fence the scheduler, then raw barrier (no implicit drain).
#define PHASE_WAIT_4()  do { asm volatile("s_waitcnt vmcnt(4)" ::: "memory"); \
    __builtin_amdgcn_sched_barrier(0); __builtin_amdgcn_s_barrier(); } while (0)
#define PHASE_WAIT_0()  do { asm volatile("s_waitcnt vmcnt(0)" ::: "memory"); \
    __builtin_amdgcn_sched_barrier(0); __builtin_amdgcn_s_barrier(); } while (0)

// async global->LDS, 16B per lane; LDS side = wave-uniform base + lane*16
__device__ __forceinline__ void gload16(const void* g, void* l) {
    __builtin_amdgcn_global_load_lds((const __attribute__((address_space(1))) void*)g,
                                     (__attribute__((address_space(3))) void*)l, 16, 0, 0);
}

// ---------------------------------------------------------------------------
// Kernel 0: convert query [16.8M], W_in [262144], W_out [524288] fp32 -> fp16
// ---------------------------------------------------------------------------
__global__ __launch_bounds__(256) void k_cvt(const float* __restrict__ query,
                                             const float* __restrict__ Wi,
                                             const float* __restrict__ Wo,
                                             f16* __restrict__ q16,
                                             f16* __restrict__ W16)
{
    int i = blockIdx.x * 256 + threadIdx.x;   // float4 index, 4390912 total
    const float4* src;
    f16* dst;
    if (i < 4194304) { src = (const float4*)query + i; dst = q16 + (size_t)i * 4; }
    else if (i < 4259840) { int j = i - 4194304; src = (const float4*)Wi + j; dst = W16 + (size_t)j * 4; }
    else { int j = i - 4259840; src = (const float4*)Wo + j; dst = W16 + 262144 + (size_t)j * 4; }
    float4 v = *src;
    half4 h = {(f16)v.x, (f16)v.y, (f16)v.z, (f16)v.w};
    *reinterpret_cast<half4*>(dst) = h;
}

// ---------------------------------------------------------------------------
// Kernel 1: q = q16 @ W16^T (fp16 gl_lds GEMM, 128x128 tile).
// v7: BK=32, 16 KiB staging buffers -> ~36 KiB LDS/block -> 4 blocks/CU
// (was 64 KiB -> 2 blocks/CU, Occupancy capped at 19%). Counted-vmcnt
// pipeline: next buffer's 4 loads stay in flight across barriers.
// ---------------------------------------------------------------------------
__global__ __launch_bounds__(256) void k_qin(const f16* __restrict__ q16,
                                             const f16* __restrict__ W16,
                                             f16* __restrict__ comb,
                                             f16* __restrict__ qT)
{
    __shared__ char sm[36864];
    const int tid = threadIdx.x, lane = tid & 63, w = tid >> 6;
    const int l15 = lane & 15, quad = lane >> 4;
    const int id = blockIdx.x, xcd = id & 7, u = id >> 3;
    const int mbase = (xcd * 32 + (u >> 2)) * 128;   // m-tile 0..255
    const int nbase = (u & 3) * 128;                 // n-tile 0..3
    const int wm = (w & 1) * 64, wn = (w >> 1) * 64;
    const int ia = (w & 1) * 4, jb = (w >> 1) * 4;

    floatx4 acc[4][4];
#pragma unroll
    for (int i = 0; i < 4; ++i)
#pragma unroll
        for (int j = 0; j < 4; ++j) acc[i][j] = (floatx4)0.f;

    auto STAGE = [&](int k0, int bsel) {   // 4 gload16 per thread
        f16* At = (f16*)(sm + bsel * 16384);
        f16* Bt = At + 4096;
#pragma unroll
        for (int jr = 0; jr < 2; ++jr) {
            int bi = jr * 4 + w;
            gload16(q16 + (size_t)(mbase + bi * 16 + l15) * 512 + k0 + quad * 8, At + bi * 512);
            gload16(W16 + (size_t)(nbase + bi * 16 + l15) * 512 + k0 + quad * 8, Bt + bi * 512);
        }
    };

    STAGE(0, 0);
    STAGE(32, 1);
    for (int it = 0; it < 16; ++it) {
        const int cur = it & 1;
        if (it < 15) PHASE_WAIT_4(); else PHASE_WAIT_0();
        f16* At = (f16*)(sm + cur * 16384);
        f16* Bt = At + 4096;
        half8 a[4], bf[4];
#pragma unroll
        for (int i = 0; i < 4; ++i)
            a[i] = *reinterpret_cast<half8*>(At + (ia + i) * 512 + lane * 8);
#pragma unroll
        for (int j = 0; j < 4; ++j)
            bf[j] = *reinterpret_cast<half8*>(Bt + (jb + j) * 512 + lane * 8);
#pragma unroll
        for (int i = 0; i < 4; ++i)
#pragma unroll
            for (int j = 0; j < 4; ++j)
                acc[i][j] = MFMA16(a[i], bf[j], acc[i][j]);
        __builtin_amdgcn_s_barrier();   // all waves done reading cur
        if (it + 2 < 16) STAGE((it + 2) * 32, cur);
    }
    const int bb = mbase >> 11, tb = mbase & 2047;
    f16* ct = (f16*)sm;   // phase A: row-major [128][136] (aliases dead staging bufs)
#pragma unroll
    for (int i = 0; i < 4; ++i)
#pragma unroll
        for (int j = 0; j < 4; ++j)
#pragma unroll
            for (int r = 0; r < 4; ++r)
                ct[(wm + i * 16 + quad * 4 + r) * 136 + wn + j * 16 + l15] = (f16)acc[i][j][r];
    __syncthreads();
#pragma unroll
    for (int it = 0; it < 8; ++it) {
        int c = it * 256 + tid, r = c >> 4, c8 = (c & 15) << 3;
        *reinterpret_cast<half8*>(comb + (size_t)(mbase + r) * 1024 + 512 + nbase + c8) =
            *reinterpret_cast<half8*>(ct + r * 136 + c8);
    }
    __syncthreads();
    // phase B: column-major [128 cols][136] — vectorized half4 dumps from acc
#pragma unroll
    for (int i = 0; i < 4; ++i)
#pragma unroll
        for (int j = 0; j < 4; ++j) {
            half4 h = {(f16)acc[i][j][0], (f16)acc[i][j][1], (f16)acc[i][j][2], (f16)acc[i][j][3]};
            *reinterpret_cast<half4*>(ct + (wn + j * 16 + l15) * 136 + wm + i * 16 + quad * 4) = h;
        }
    __syncthreads();
    // qT writes: 16 lanes share a d-row -> 256 B contiguous global segments
#pragma unroll
    for (int it = 0; it < 8; ++it) {
        int c = it * 256 + tid, dd = c >> 4, tc = (c & 15) << 3;
        *reinterpret_cast<half8*>(qT + ((size_t)bb * 512 + nbase + dd) * 2048 + tb + tc) =
            *reinterpret_cast<half8*>(ct + dd * 136 + tc);
    }
}

// ---------------------------------------------------------------------------
// Kernel 2: fused S-tile GEMM + PER-TILE softmax (parallel flash).
// One block per (b, causal tile), grid (16,136). v7: BK=32 staging
// (~36 KiB LDS -> 4 blocks/CU) + counted-vmcnt pipeline. Register
// epilogue: tile-local masked row max m_t, P_t = exp(S_t - m_t) fp16
// (cached stores: re-read by k_pscale + k_pv), row sums l_t.
// ---------------------------------------------------------------------------
__global__ __launch_bounds__(256) void k_sgemmsm(const f16* __restrict__ comb,
                                                 f16* __restrict__ Pd,
                                                 float* __restrict__ Mt,
                                                 float* __restrict__ Lt)
{
    __shared__ char sm[36864];
    const int tid = threadIdx.x, lane = tid & 63, w = tid >> 6;
    const int l15 = lane & 15, quad = lane >> 4;
    const int wm = (w & 1) * 64, wn = (w >> 1) * 64;
    const int ia = (w & 1) * 4, jb = (w >> 1) * 4;

    int bx = blockIdx.y, mt = 0;
    while ((mt + 1) * (mt + 2) / 2 <= bx) ++mt;
    const int nt = bx - mt * (mt + 1) / 2;
    const int b = blockIdx.x;   // grid (16,136): id&7 = b&7 -> batch/XCD pin
    const f16* qa = comb + ((size_t)b * 2048 + mt * 128) * 1024 + 512;
    const f16* qb = comb + ((size_t)b * 2048 + nt * 128) * 1024 + 512;

    floatx4 acc[4][4];
#pragma unroll
    for (int i = 0; i < 4; ++i)
#pragma unroll
        for (int j = 0; j < 4; ++j) acc[i][j] = (floatx4)0.f;

    auto STAGE = [&](int k0, int bsel) {   // 4 gload16 per thread
        f16* At = (f16*)(sm + bsel * 16384);
        f16* Bt = At + 4096;
#pragma unroll
        for (int jr = 0; jr < 2; ++jr) {
            int bi = jr * 4 + w;
            gload16(qa + (size_t)(bi * 16 + l15) * 1024 + k0 + quad * 8, At + bi * 512);
            gload16(qb + (size_t)(bi * 16 + l15) * 1024 + k0 + quad * 8, Bt + bi * 512);
        }
    };

    STAGE(0, 0);
    STAGE(32, 1);
    for (int it = 0; it < 16; ++it) {
        const int cur = it & 1;
        if (it < 15) PHASE_WAIT_4(); else PHASE_WAIT_0();
        f16* At = (f16*)(sm + cur * 16384);
        f16* Bt = At + 4096;
        half8 a[4], bf[4];
#pragma unroll
        for (int i = 0; i < 4; ++i)
            a[i] = *reinterpret_cast<half8*>(At + (ia + i) * 512 + lane * 8);
#pragma unroll
        for (int j = 0; j < 4; ++j)
            bf[j] = *reinterpret_cast<half8*>(Bt + (jb + j) * 512 + lane * 8);
#pragma unroll
        for (int i = 0; i < 4; ++i)
#pragma unroll
            for (int j = 0; j < 4; ++j)
                acc[i][j] = MFMA16(a[i], bf[j], acc[i][j]);
        __builtin_amdgcn_s_barrier();
        if (it + 2 < 16) STAGE((it + 2) * 32, cur);
    }

    // ---- per-tile softmax epilogue ----
    const bool diag = (nt == mt);
    f16* ct = (f16*)sm;                   // [128][136], aliases dead staging
    float* redm = (float*)(sm + 34816);   // [4 waves][64 rows] partial max
    float* reds = (float*)(sm + 35840);   // [4 waves][64 rows] partial sum
    const int hb = w & 1;

    // masked wave-partial row max (reduce over j regs + l15 lanes)
    float wmax[4][4];
#pragma unroll
    for (int i = 0; i < 4; ++i)
#pragma unroll
        for (int r = 0; r < 4; ++r) {
            const int rowl = wm + i * 16 + quad * 4 + r;
            float mm = -1e38f;
#pragma unroll
            for (int j = 0; j < 4; ++j) {
                float v = acc[i][j][r];
                if (diag && (wn + j * 16 + l15) >= rowl) v = -1e38f;
                mm = fmaxf(mm, v);
            }
            mm = fmaxf(mm, __shfl_xor(mm, 1));
            mm = fmaxf(mm, __shfl_xor(mm, 2));
            mm = fmaxf(mm, __shfl_xor(mm, 4));
            mm = fmaxf(mm, __shfl_xor(mm, 8));
            wmax[i][r] = mm;
        }
    if (l15 == 0)
#pragma unroll
        for (int i = 0; i < 4; ++i)
#pragma unroll
            for (int r = 0; r < 4; ++r)
                redm[w * 64 + i * 16 + quad * 4 + r] = wmax[i][r];
    __syncthreads();

    // exp + P->ct + row partial sums
#pragma unroll
    for (int i = 0; i < 4; ++i)
#pragma unroll
        for (int r = 0; r < 4; ++r) {
            const int idx = i * 16 + quad * 4 + r;
            const int rowl = wm + idx;
            const float m = fmaxf(redm[hb * 64 + idx], redm[(hb + 2) * 64 + idx]);
            float ssum = 0.f;
#pragma unroll
            for (int j = 0; j < 4; ++j) {
                const int col = wn + j * 16 + l15;
                const bool valid = !diag || (col < rowl);
                float e = valid ? __expf(acc[i][j][r] - m) : 0.f;
                ssum += e;
                ct[rowl * 136 + col] = (f16)e;
            }
            ssum += __shfl_xor(ssum, 1);
            ssum += __shfl_xor(ssum, 2);
            ssum += __shfl_xor(ssum, 4);
            ssum += __shfl_xor(ssum, 8);
            wmax[i][r] = ssum;   // reuse as sum stash
        }
    if (l15 == 0)
#pragma unroll
        for (int i = 0; i < 4; ++i)
#pragma unroll
            for (int r = 0; r < 4; ++r)
                reds[w * 64 + i * 16 + quad * 4 + r] = wmax[i][r];
    __syncthreads();

    // m/l tables: one thread per row, contiguous 512B stores
    if (tid < 128) {
        const int h2 = tid >> 6, i2 = tid & 63;
        const float mm = fmaxf(redm[h2 * 64 + i2], redm[(h2 + 2) * 64 + i2]);
        const float ll = reds[h2 * 64 + i2] + reds[(h2 + 2) * 64 + i2];
        const size_t o = (((size_t)b * 16 + nt) << 11) + mt * 128 + tid;
        Mt[o] = mm;
        Lt[o] = ll;
    }
    // P' tile -> dense fp16 [b][tile][128][128], cached stores
    f16* Pt = Pd + ((size_t)(b * 136 + bx) << 14);
#pragma unroll
    for (int itp = 0; itp < 8; ++itp) {
        int c = itp * 256 + tid, r_ = c >> 4, c8 = (c & 15) << 3;
        *reinterpret_cast<half8*>(Pt + r_ * 128 + c8) =
            *reinterpret_cast<half8*>(ct + r_ * 136 + c8);
    }
}

// ---------------------------------------------------------------------------
// Kernel 3: combine per-tile stats -> per-tile scale factors, IN PLACE:
// F[b][t][row] = exp(m_t - M) / l  (0 if l==0, i.e. global row 0).
// M = max_t m_t, l = sum_t l_t * exp(m_t - M). One thread per row.
// ---------------------------------------------------------------------------
__global__ __launch_bounds__(256) void k_stats(float* Mt, const float* __restrict__ Lt)
{
    const int b = blockIdx.x, row = blockIdx.y * 256 + threadIdx.x;
    const int mtr = row >> 7;
    float mv[16], lv[16];
    for (int t = 0; t <= mtr; ++t) {
        const size_t o = (((size_t)b * 16 + t) << 11) + row;
        mv[t] = Mt[o];
        lv[t] = Lt[o];
    }
    float M = -1e38f;
    for (int t = 0; t <= mtr; ++t) M = fmaxf(M, mv[t]);
    float l = 0.f;
    for (int t = 0; t <= mtr; ++t) l += lv[t] * __expf(mv[t] - M);
    const float invl = (l > 0.f) ? 1.f / l : 0.f;
    for (int t = 0; t <= mtr; ++t)
        Mt[(((size_t)b * 16 + t) << 11) + row] = __expf(mv[t] - M) * invl;
}

// ---------------------------------------------------------------------------
// Kernel 3b: pre-scale P' rows by F -> P'' = final softmax weights.
// Grid (16,136) = same XCD pin as producer -> L2-hot.
// Tile (b, bx=(mt,nt)): row r scaled by F[b][nt][mt*128+r].
// ---------------------------------------------------------------------------
__global__ __launch_bounds__(256) void k_pscale(f16* __restrict__ Pd,
                                               const float* __restrict__ Ft)
{
    int bx = blockIdx.y, mt = 0;
    while ((mt + 1) * (mt + 2) / 2 <= bx) ++mt;
    const int nt = bx - mt * (mt + 1) / 2;
    const int b = blockIdx.x;
    const int tid = threadIdx.x;
    const int row = tid >> 1, c0 = (tid & 1) * 64;   // 2 threads/row, 64 halves each
    const float Fv = Ft[(((size_t)b * 16 + nt) << 11) + mt * 128 + row];
    f16* Pt = Pd + ((size_t)(b * 136 + bx) << 14) + (size_t)row * 128 + c0;
#pragma unroll
    for (int c = 0; c < 8; ++c) {
        half8 h = *reinterpret_cast<half8*>(Pt + c * 8);
#pragma unroll
        for (int e = 0; e < 8; ++e) h[e] = (f16)((float)h[e] * Fv);
        *reinterpret_cast<half8*>(Pt + c * 8) = h;
    }
}

// ---------------------------------------------------------------------------
// Kernel 4: mix = P'' @ qT — pure GEMM (F pre-folded by k_pscale).
// v7: BK=32 staging (~34 KiB LDS -> 4 blocks/CU) + counted-vmcnt pipeline.
// Uniform-work pairing (mt=p with 15-p: 68 K-iters/block, 512 blocks).
// ---------------------------------------------------------------------------
__global__ __launch_bounds__(256) void k_pv(const f16* __restrict__ Pd,
                                            const f16* __restrict__ qT,
                                            f16* __restrict__ comb)
{
    __shared__ char sm[34816];
    const int tid = threadIdx.x, lane = tid & 63, w = tid >> 6;
    const int l15 = lane & 15, quad = lane >> 4;
    const int wm = (w & 1) * 64, wn = (w >> 1) * 64;
    const int ia = (w & 1) * 4, jb = (w >> 1) * 4;
    const int id = blockIdx.x;
    const int p = id & 7, nb = (id >> 3) & 3, b = id >> 5;
    const f16* Pdb = Pd + ((size_t)b * 136 << 14);
    const f16* qTb = qT + ((size_t)b * 512 + nb * 128) * 2048;

    for (int t = 0; t < 2; ++t) {
        const int mt = t ? (15 - p) : p;
        const int tb0 = mt * (mt + 1) / 2;
        const int kit = (mt + 1) * 4;

        floatx4 acc[4][4];
#pragma unroll
        for (int i = 0; i < 4; ++i)
#pragma unroll
            for (int j = 0; j < 4; ++j) acc[i][j] = (floatx4)0.f;

        auto STAGE = [&](int it, int bsel) {   // 4 gload16 per thread
            f16* At = (f16*)(sm + bsel * 16384);
            f16* Bt = At + 4096;
            const int k0 = it * 32;
#pragma unroll
            for (int jr = 0; jr < 2; ++jr) {
                int bi = jr * 4 + w;
                gload16(Pdb + ((size_t)(tb0 + (k0 >> 7)) << 14) + (size_t)(bi * 16 + l15) * 128
                            + (k0 & 96) + quad * 8,
                        At + bi * 512);
                gload16(qTb + (size_t)(bi * 16 + l15) * 2048 + k0 + quad * 8, Bt + bi * 512);
            }
        };

        STAGE(0, 0);
        STAGE(1, 1);
        for (int it = 0; it < kit; ++it) {
            const int cur = it & 1;
            if (it < kit - 1) PHASE_WAIT_4(); else PHASE_WAIT_0();
            f16* At = (f16*)(sm + cur * 16384);
            f16* Bt = At + 4096;
            half8 a[4], bf[4];
#pragma unroll
            for (int i = 0; i < 4; ++i)
                a[i] = *reinterpret_cast<half8*>(At + (ia + i) * 512 + lane * 8);
#pragma unroll
            for (int j = 0; j < 4; ++j)
                bf[j] = *reinterpret_cast<half8*>(Bt + (jb + j) * 512 + lane * 8);
#pragma unroll
            for (int i = 0; i < 4; ++i)
#pragma unroll
                for (int j = 0; j < 4; ++j)
                    acc[i][j] = MFMA16(a[i], bf[j], acc[i][j]);
            __builtin_amdgcn_s_barrier();   // all waves done reading cur
            if (it + 2 < kit) STAGE(it + 2, cur);
        }

        // epilogue: bounce via ct (aliases dead staging bufs), store comb
        f16* ct = (f16*)sm;
#pragma unroll
        for (int i = 0; i < 4; ++i)
#pragma unroll
            for (int j = 0; j < 4; ++j)
#pragma unroll
                for (int r = 0; r < 4; ++r)
                    ct[(wm + i * 16 + quad * 4 + r) * 136 + wn + j * 16 + l15] = (f16)acc[i][j][r];
        __syncthreads();
#pragma unroll
        for (int it = 0; it < 8; ++it) {
            int c = it * 256 + tid, r = c >> 4, c8 = (c & 15) << 3;
            *reinterpret_cast<half8*>(comb + ((size_t)b * 2048 + mt * 128 + r) * 1024 + nb * 128 + c8) =
                *reinterpret_cast<half8*>(ct + r * 136 + c8);
        }
        __syncthreads();   // ct reads done before next tile re-stages over it
    }
}

// ---------------------------------------------------------------------------
// Kernel 5: out = comb @ W_out^T (fp16 gl_lds GEMM, fp32 out). K=1024.
// v7: BK=32 staging (~33 KiB LDS -> 4 blocks/CU) + counted-vmcnt pipeline.
// NT full-line output stores (out never re-read on device -> NT correct here).
// ---------------------------------------------------------------------------
__global__ __launch_bounds__(256) void k_out(const f16* __restrict__ comb,
                                             const f16* __restrict__ Wo16,
                                             float* __restrict__ out)
{
    __shared__ char sm[33792];
    const int tid = threadIdx.x, lane = tid & 63, w = tid >> 6;
    const int l15 = lane & 15, quad = lane >> 4;
    const int id = blockIdx.x, xcd = id & 7, u = id >> 3;
    const int mbase = (xcd * 32 + (u >> 2)) * 128;
    const int nbase = (u & 3) * 128;
    const int wm = (w & 1) * 64, wn = (w >> 1) * 64;
    const int ia = (w & 1) * 4, jb = (w >> 1) * 4;

    floatx4 acc[4][4];
#pragma unroll
    for (int i = 0; i < 4; ++i)
#pragma unroll
        for (int j = 0; j < 4; ++j) acc[i][j] = (floatx4)0.f;

    auto STAGE = [&](int k0, int bsel) {   // 4 gload16 per thread
        f16* At = (f16*)(sm + bsel * 16384);
        f16* Bt = At + 4096;
#pragma unroll
        for (int jr = 0; jr < 2; ++jr) {
            int bi = jr * 4 + w;
            gload16(comb + (size_t)(mbase + bi * 16 + l15) * 1024 + k0 + quad * 8, At + bi * 512);
            gload16(Wo16 + (size_t)(nbase + bi * 16 + l15) * 1024 + k0 + quad * 8, Bt + bi * 512);
        }
    };

    STAGE(0, 0);
    STAGE(32, 1);
    for (int it = 0; it < 32; ++it) {
        const int cur = it & 1;
        if (it < 31) PHASE_WAIT_4(); else PHASE_WAIT_0();
        f16* At = (f16*)(sm + cur * 16384);
        f16* Bt = At + 4096;
        half8 a[4], bf[4];
#pragma unroll
        for (int i = 0; i < 4; ++i)
            a[i] = *reinterpret_cast<half8*>(At + (ia + i) * 512 + lane * 8);
#pragma unroll
        for (int j = 0; j < 4; ++j)
            bf[j] = *reinterpret_cast<half8*>(Bt + (jb + j) * 512 + lane * 8);
#pragma unroll
        for (int i = 0; i < 4; ++i)
#pragma unroll
            for (int j = 0; j < 4; ++j)
                acc[i][j] = MFMA16(a[i], bf[j], acc[i][j]);
        __builtin_amdgcn_s_barrier();
        if (it + 2 < 32) STAGE((it + 2) * 32, cur);
    }
    float* cf = (float*)sm;   // [64][132] fp32 padded
    for (int pass = 0; pass < 2; ++pass) {
        __syncthreads();
        if ((w & 1) == pass) {
#pragma unroll
            for (int i = 0; i < 4; ++i)
#pragma unroll
                for (int j = 0; j < 4; ++j)
#pragma unroll
                    for (int r = 0; r < 4; ++r)
                        cf[(i * 16 + quad * 4 + r) * 132 + wn + j * 16 + l15] = acc[i][j][r];
        }
        __syncthreads();
#pragma unroll
        for (int it = 0; it < 8; ++it) {
            int c = it * 256 + tid, row = c >> 5, c4 = (c & 31) << 2;
            __builtin_nontemporal_store(
                *reinterpret_cast<floatx4*>(cf + row * 132 + c4),
                reinterpret_cast<floatx4*>(out + (size_t)(mbase + pass * 64 + row) * 512 + nbase + c4));
        }
    }
}

extern "C" void kernel_launch(void* const* d_in, const int* in_sizes, int n_in,
                              void* d_out, int out_size, void* d_ws, size_t ws_size,
                              hipStream_t stream)
{
    const float* query = (const float*)d_in[0];
    const float* W_in  = (const float*)d_in[1];
    const float* W_out = (const float*)d_in[2];
    float* out = (float*)d_out;

    // ws layout (bytes):
    //   comb fp16 [32768][1024] (mix|q)        @ 0           (67,108,864)
    //   qT   fp16 [16][512][2048]              @ 67,108,864  (33,554,432)
    //   W16  fp16 [Wi 262144 | Wo 524288]      @ 100,663,296 (1,572,864)
    //   X    @ 102,236,160:
    //     q16 fp16 [16*2048*512] (33,554,432)  -- dead after k_qin
    //     Pd  fp16 [16][136][128][128]         @ XOFF        (71,303,168) aliases q16
    //     Mt  f32  [16][16][2048] (m_t -> F_t) @ +71,303,168 (2,097,152)
    //     Lt  f32  [16][16][2048] (l_t)        @ +73,400,320 (2,097,152)
    const size_t XOFF = 102236160ull;
    f16* comb = (f16*)d_ws;
    f16* qT   = comb + (size_t)32768 * 1024;
    f16* W16  = qT + (size_t)16 * 512 * 2048;
    f16* q16  = (f16*)((char*)d_ws + XOFF);
    f16* Pd   = (f16*)((char*)d_ws + XOFF);
    float* Mt = (float*)((char*)d_ws + XOFF + 71303168ull);
    float* Lt = (float*)((char*)d_ws + XOFF + 73400320ull);

    k_cvt<<<17152, 256, 0, stream>>>(query, W_in, W_out, q16, W16);
    k_qin<<<1024, 256, 0, stream>>>(q16, W16, comb, qT);
    k_sgemmsm<<<dim3(16, 136), 256, 0, stream>>>(comb, Pd, Mt, Lt);
    k_stats<<<dim3(16, 8), 256, 0, stream>>>(Mt, Lt);
    k_pscale<<<dim3(16, 136), 256, 0, stream>>>(Pd, Mt);
    k_pv<<<512, 256, 0, stream>>>(Pd, qT, comb);
    k_out<<<1024, 256, 0, stream>>>(comb, W16 + 262144, out);
}